// Round 1
// 59.651 us; speedup vs baseline: 1.0114x; 1.0114x over previous
//
#include <hip/hip_runtime.h>
#include <cmath>

// ADF tanh moment propagation.
// Reference: 128-pt Gauss-Hermite. We use trapezoid quadrature on the
// Gaussian integral: h=0.5, nodes x=-3..3 (13 pts), weights ∝ exp(-x^2),
// normalized to sum 1.
//  - pole term (tanh/tanh^2 poles at Im z = pi/2): measured ~3.9e-3 absmax
//    at h=0.5 (dominates; scales ~e^{-2*pi*1.11/h}, so h must stay 0.5)
//  - truncation at |x|=3: <= erfc(3) ~= 2.2e-5 — negligible.
// Threshold is 1.52e-2 absolute => ~4x margin, deterministic.
//
// R1 change: nodes are UNIFORMLY spaced, so the 13 exponentials form a
// geometric sequence: exp2(kz_q) = e0 * R^q with R = exp2(K*sqrt2*h*s)
// computed once. 13 v_exp_f32 -> 2 v_exp_f32 + 12 v_mul_f32.
// Also accumulate in r = 1/(e+1) space:
//   tanh = 1 - 2r  =>  m1 = 1 - 2*S1,  m2 = 1 - 4*S1 + 4*S2
//   with S1 = sum w*r, S2 = sum w*r^2  (kills the per-node tanh fma).
// Recurrence error: <= 12 ulp relative on e, |d tanh / d ln e| <= 0.5
// => ~<1e-6 added error, invisible vs 3.9e-3 quadrature error.
// Range: kz in [-12.25, 15.2] => e in [2^-12.3, 2^15.2], no overflow.

#define NQ 13

struct QTable {
    float w[NQ];   // normalized weights, sum to 1
    float kmin;    // K*sqrt2*h*(-(NQ-1)/2) = -12.2427  (coeff of s for node 0)
    float kstep;   // K*sqrt2*h = 2.040446               (per-node increment coeff)
};

#if __has_builtin(__builtin_amdgcn_exp2f)
__device__ __forceinline__ float fast_exp2(float x) { return __builtin_amdgcn_exp2f(x); }
#else
__device__ __forceinline__ float fast_exp2(float x) { return exp2f(x); }
#endif
#if __has_builtin(__builtin_amdgcn_rcpf)
__device__ __forceinline__ float fast_rcp(float x) { return __builtin_amdgcn_rcpf(x); }
#else
__device__ __forceinline__ float fast_rcp(float x) { return 1.0f / x; }
#endif
#if __has_builtin(__builtin_amdgcn_sqrtf)
__device__ __forceinline__ float fast_sqrt(float x) { return __builtin_amdgcn_sqrtf(x); }
#else
__device__ __forceinline__ float fast_sqrt(float x) { return sqrtf(x); }
#endif

__global__ __launch_bounds__(256) void adf_tanh_kernel(
    const float* __restrict__ X, float* __restrict__ out,
    int n, int n4, int nthreads, QTable T)
{
    constexpr float K = 2.8853900817779268f;  // 2/ln(2) = 2*log2(e)
    int i = blockIdx.x * 256 + threadIdx.x;

    if (i < n4) {
        // vectorized path: 4 elements per thread, rows are 16B-aligned (n%4==0)
        float4 mu4 = ((const float4*)X)[i];
        float4 vv4 = *((const float4*)(X + n) + i);
        float mu[4] = {mu4.x, mu4.y, mu4.z, mu4.w};
        float vv[4] = {vv4.x, vv4.y, vv4.z, vv4.w};
        float e[4], R[4], S1[4], S2[4];
#pragma unroll
        for (int j = 0; j < 4; ++j) {
            float s = fast_sqrt(vv[j]);
            e[j]  = fast_exp2(fmaf(T.kmin, s, K * mu[j]));  // exp at lowest node
            R[j]  = fast_exp2(T.kstep * s);                 // per-node ratio
            S1[j] = 0.0f;
            S2[j] = 0.0f;
        }
#pragma unroll
        for (int q = 0; q < NQ; ++q) {
            float w = T.w[q];
#pragma unroll
            for (int j = 0; j < 4; ++j) {
                float r = fast_rcp(e[j] + 1.0f);
                S1[j] = fmaf(w, r, S1[j]);
                S2[j] = fmaf(w * r, r, S2[j]);
                if (q < NQ - 1) e[j] *= R[j];   // geometric walk to next node
            }
        }
        float4 o1, o2;
        float m1[4], m2[4];
#pragma unroll
        for (int j = 0; j < 4; ++j) {
            m1[j] = fmaf(-2.0f, S1[j], 1.0f);
            m2[j] = fmaf(4.0f, S2[j], fmaf(-4.0f, S1[j], 1.0f));
        }
        o1.x = m1[0]; o1.y = m1[1]; o1.z = m1[2]; o1.w = m1[3];
        o2.x = fmaf(-m1[0], m1[0], m2[0]);
        o2.y = fmaf(-m1[1], m1[1], m2[1]);
        o2.z = fmaf(-m1[2], m1[2], m2[2]);
        o2.w = fmaf(-m1[3], m1[3], m2[3]);
        ((float4*)out)[i] = o1;
        *((float4*)(out + n) + i) = o2;
    } else if (i < nthreads) {
        // scalar tail (n % 4 leftovers, or whole array if rows not 16B-aligned)
        int e_idx = 4 * n4 + (i - n4);
        float mu = X[e_idx];
        float vv = X[n + e_idx];
        float s = fast_sqrt(vv);
        float e = fast_exp2(fmaf(T.kmin, s, K * mu));
        float R = fast_exp2(T.kstep * s);
        float S1 = 0.0f, S2 = 0.0f;
#pragma unroll
        for (int q = 0; q < NQ; ++q) {
            float r = fast_rcp(e + 1.0f);
            S1 = fmaf(T.w[q], r, S1);
            S2 = fmaf(T.w[q] * r, r, S2);
            if (q < NQ - 1) e *= R;
        }
        float m1 = fmaf(-2.0f, S1, 1.0f);
        float m2 = fmaf(4.0f, S2, fmaf(-4.0f, S1, 1.0f));
        out[e_idx] = m1;
        out[n + e_idx] = fmaf(-m1, m1, m2);
    }
}

static QTable make_table() {
    QTable t;
    const double h = 0.5;
    const double K = 2.0 / std::log(2.0);     // 2*log2(e)
    const double s2 = std::sqrt(2.0);
    double wraw[NQ];
    double wsum = 0.0;
    for (int q = 0; q < NQ; ++q) {
        double x = h * (double)(q - (NQ - 1) / 2);  // -3.0 .. 3.0
        wraw[q] = std::exp(-x * x);
        wsum += wraw[q];
    }
    for (int q = 0; q < NQ; ++q) t.w[q] = (float)(wraw[q] / wsum);
    t.kstep = (float)(K * s2 * h);                          //  2.040446
    t.kmin  = (float)(-K * s2 * h * (double)((NQ - 1) / 2)); // -12.242676
    return t;
}

extern "C" void kernel_launch(void* const* d_in, const int* in_sizes, int n_in,
                              void* d_out, int out_size, void* d_ws, size_t ws_size,
                              hipStream_t stream) {
    (void)n_in; (void)d_ws; (void)ws_size; (void)out_size;
    const float* X = (const float*)d_in[0];
    float* out = (float*)d_out;
    int n = in_sizes[0] / 2;                  // 1,000,000

    static QTable T = make_table();           // host-side constants, same every call

    int n4 = (n % 4 == 0) ? (n / 4) : 0;      // float4 path needs 16B-aligned rows
    int rem = n - 4 * n4;
    int nthreads = n4 + rem;
    int grid = (nthreads + 255) / 256;

    adf_tanh_kernel<<<grid, 256, 0, stream>>>(X, out, n, n4, nthreads, T);
}